// Round 5
// baseline (244.973 us; speedup 1.0000x reference)
//
#include <hip/hip_runtime.h>
#include <hip/hip_fp16.h>
#include <cstdint>

#define T_STEPS 32
#define NB 64
#define STATE 64
#define HID 128
#define ACT 32
#define CDIM 96
#define G3 (3*HID)   // 384

typedef __attribute__((ext_vector_type(8))) short short8;
typedef __attribute__((ext_vector_type(4))) float f32x4;
typedef _Float16 h2v __attribute__((ext_vector_type(2)));

__device__ __forceinline__ unsigned short f2bf(float f){
  unsigned int u = __builtin_bit_cast(unsigned int, f);
  u = u + 0x7FFFu + ((u >> 16) & 1u);
  return (unsigned short)(u >> 16);
}
__device__ __forceinline__ float bf2f(unsigned short u){
  unsigned int v = ((unsigned int)u) << 16; return __builtin_bit_cast(float, v);
}
__device__ __forceinline__ unsigned int packh2(float f0, float f1){
  return (unsigned int)__half_as_ushort(__float2half_rn(f0)) |
         ((unsigned int)__half_as_ushort(__float2half_rn(f1)) << 16);
}
__device__ __forceinline__ float sigmoidf_(float x){ return 1.0f/(1.0f + __expf(-x)); }
__device__ __forceinline__ float tanhf_(float x){ float e = __expf(2.0f*x); return (e-1.0f)/(e+1.0f); }

__device__ __forceinline__ float dot2f(float acc, unsigned int a, unsigned int b){
  h2v av = __builtin_bit_cast(h2v, a);
  h2v bv = __builtin_bit_cast(h2v, b);
  return __builtin_amdgcn_fdot2(av, bv, acc, false);
}
__device__ __forceinline__ float l1d(float acc, unsigned int ua, unsigned int ub){
  __half2 a = __builtin_bit_cast(__half2, ua);
  __half2 b = __builtin_bit_cast(__half2, ub);
  __half2 d = __habs2(__hsub2(a, b));
  h2v dv = __builtin_bit_cast(h2v, d);
  h2v ones; ones[0] = (_Float16)1.0f; ones[1] = (_Float16)1.0f;
  return __builtin_amdgcn_fdot2(dv, ones, acc, false);
}
__device__ __forceinline__ float l1d4(float acc, uint4 a, uint4 b){
  acc = l1d(acc, a.x, b.x); acc = l1d(acc, a.y, b.y);
  acc = l1d(acc, a.z, b.z); acc = l1d(acc, a.w, b.w);
  return acc;
}

// ---------------- prep ----------------
// blocks 0..127   : tmh  (Tm -> bf16 MFMA B-frag order, per b)
// blocks 128..135 : GRU weights fp16-packed (wih0p, whh0p, wih1p, whh1p)
// blocks 136..139 : w1 -> bf16 B-frag order (w1f)
// blocks 140..151 : a  -> bf16 A-frag chunks 16..19 of h1af
__global__ void k_prep(const float* __restrict__ Tm, unsigned short* __restrict__ tmh,
                       const float* __restrict__ wih0, const float* __restrict__ whh0,
                       const float* __restrict__ wih1, const float* __restrict__ whh1,
                       const float* __restrict__ w1, const float* __restrict__ a,
                       unsigned int* __restrict__ wih0p, unsigned int* __restrict__ whh0p,
                       unsigned int* __restrict__ wih1p, unsigned int* __restrict__ whh1p,
                       unsigned short* __restrict__ w1f, unsigned short* __restrict__ h1af){
  int tid = threadIdx.x;
  int bx = blockIdx.x;
  if (bx < 128){
    int b = bx;
    for (int e = tid; e < HID*CDIM; e += 256){
      int chunk = e / 768;
      int r1 = e - chunk*768;
      int c = r1 >> 3, h = r1 & 7;
      int k = chunk*8 + h;
      tmh[b*(HID*CDIM) + e] = f2bf(Tm[k*(HID*CDIM) + b*CDIM + c]);
    }
  } else if (bx < 136){
    int mb = bx - 128;   // 0..7
    const float* srcs[4] = {wih0, whh0, wih1, whh1};
    unsigned int* dsts[4] = {wih0p, whh0p, wih1p, whh1p};
    const int K2s[4] = {32,64,64,64};
    for (int mm = 0; mm < 4; mm++){
      const float* s = srcs[mm]; unsigned int* d = dsts[mm];
      int K2 = K2s[mm], tot = 384*K2;
      for (int e = mb*256 + tid; e < tot; e += 8*256){
        int k2 = e / 384, r = e - k2*384;
        d[e] = packh2(s[r*(2*K2) + 2*k2], s[r*(2*K2) + 2*k2 + 1]);
      }
    }
  } else if (bx < 140){
    // w1f[kchunk*1024 + col*8 + j] = bf16(w1[col][kchunk*8+j]), kchunk<20, col<128
    int mb = bx - 136;
    for (int e = mb*256 + tid; e < 20480; e += 4*256){
      int kchunk = e >> 10, rem = e & 1023;
      int col = rem >> 3, j = rem & 7;
      w1f[e] = f2bf(w1[col*160 + kchunk*8 + j]);
    }
  } else {
    // a-part of h1af: k = 128+c
    int mb = bx - 140;   // 0..11
    for (int e = mb*256 + tid; e < 65536; e += 12*256){
      int t = e >> 11, rem = e & 2047;
      int n = rem >> 5, c = rem & 31;
      int pos = t*10240 + (n>>4)*2560 + (16 + (c>>3))*128 + (n&15)*8 + (c&7);
      h1af[pos] = f2bf(a[t*(NB*ACT) + n*ACT + c]);
    }
  }
}

// ---------------- fused 2-layer GRU: one block per sample ----------------
// thread = (r = tid>>1, kh = tid&1). Per step: phaseA {gh0,gi0,gh1} -> gates0 -> h0(t)
// -> phaseB {gi1 = wih1*h0(t)} -> gates1 -> h1(t) (+ bf16 A-frag emission for fc1).
__global__ __launch_bounds__(768, 3) void k_gruF(const float* __restrict__ x,
                                                 const unsigned int* __restrict__ wih0p,
                                                 const unsigned int* __restrict__ whh0p,
                                                 const unsigned int* __restrict__ wih1p,
                                                 const unsigned int* __restrict__ whh1p,
                                                 const float* __restrict__ bih0, const float* __restrict__ bhh0,
                                                 const float* __restrict__ bih1, const float* __restrict__ bhh1,
                                                 unsigned short* __restrict__ h1af){
  __shared__ __align__(16) unsigned int h0l[64];
  __shared__ __align__(16) unsigned int h1l[64];
  __shared__ __align__(16) unsigned int xall[1024];
  __shared__ float A0[G3], B0[G3], C1[G3];
  int n = blockIdx.x, tid = threadIdx.x;
  int r = tid >> 1, kh = tid & 1;
  unsigned int wi0[16], wh0[32], wi1[32], wh1[32];
  #pragma unroll
  for (int i = 0; i < 16; i++) wi0[i] = wih0p[(kh*16 + i)*384 + r];
  #pragma unroll
  for (int i = 0; i < 32; i++) wh0[i] = whh0p[(kh*32 + i)*384 + r];
  #pragma unroll
  for (int i = 0; i < 32; i++) wi1[i] = wih1p[(kh*32 + i)*384 + r];
  #pragma unroll
  for (int i = 0; i < 32; i++) wh1[i] = whh1p[(kh*32 + i)*384 + r];
  float bh0v = (kh == 0) ? bhh0[r] : 0.0f;
  float bi0v = (kh == 0) ? bih0[r] : 0.0f;
  float bi1v = (kh == 0) ? bih1[r] : 0.0f;
  float bh1v = (kh == 0) ? bhh1[r] : 0.0f;
  for (int e = tid; e < 1024; e += 768){
    int t_ = e >> 5, i = e & 31;
    const float* xp = x + t_*(NB*STATE) + n*STATE + 2*i;
    xall[e] = packh2(xp[0], xp[1]);
  }
  if (tid < 64){ h0l[tid] = 0u; h1l[tid] = 0u; }
  float h0prev = 0.0f, h1prev = 0.0f;
  __syncthreads();
  const uint4* h04 = (const uint4*)h0l;
  const uint4* h14 = (const uint4*)h1l;
  const uint4* xl4 = (const uint4*)xall;
  for (int t = 0; t < T_STEPS; t++){
    // ---- phase A: gh0 (whh0*h0prev), gi0 (wih0*x_t), gh1 (whh1*h1prev)
    float gh0 = bh0v, gi0 = bi0v, gh1 = bh1v;
    #pragma unroll
    for (int g = 0; g < 2; g++){
      uint4 hv0[4], hv1[4];
      #pragma unroll
      for (int j = 0; j < 4; j++){ hv0[j] = h04[kh*8 + g*4 + j]; hv1[j] = h14[kh*8 + g*4 + j]; }
      #pragma unroll
      for (int j = 0; j < 4; j++){
        gh0 = dot2f(gh0, wh0[g*16 + j*4 + 0], hv0[j].x);
        gh0 = dot2f(gh0, wh0[g*16 + j*4 + 1], hv0[j].y);
        gh0 = dot2f(gh0, wh0[g*16 + j*4 + 2], hv0[j].z);
        gh0 = dot2f(gh0, wh0[g*16 + j*4 + 3], hv0[j].w);
        gh1 = dot2f(gh1, wh1[g*16 + j*4 + 0], hv1[j].x);
        gh1 = dot2f(gh1, wh1[g*16 + j*4 + 1], hv1[j].y);
        gh1 = dot2f(gh1, wh1[g*16 + j*4 + 2], hv1[j].z);
        gh1 = dot2f(gh1, wh1[g*16 + j*4 + 3], hv1[j].w);
      }
    }
    #pragma unroll
    for (int j = 0; j < 4; j++){
      uint4 xv = xl4[t*8 + kh*4 + j];
      gi0 = dot2f(gi0, wi0[j*4 + 0], xv.x);
      gi0 = dot2f(gi0, wi0[j*4 + 1], xv.y);
      gi0 = dot2f(gi0, wi0[j*4 + 2], xv.z);
      gi0 = dot2f(gi0, wi0[j*4 + 3], xv.w);
    }
    gh0 += __shfl_xor(gh0, 1);
    gi0 += __shfl_xor(gi0, 1);
    gh1 += __shfl_xor(gh1, 1);
    if (kh == 0){ A0[r] = gh0; B0[r] = gi0; C1[r] = gh1; }
    __syncthreads();
    // ---- gates layer 0
    if (tid < HID){
      float rg = sigmoidf_(B0[tid]       + A0[tid]);
      float z  = sigmoidf_(B0[tid+HID]   + A0[tid+HID]);
      float nn = tanhf_   (B0[tid+2*HID] + rg*A0[tid+2*HID]);
      float hn = (1.0f - z)*nn + z*h0prev;
      h0prev = hn;
      ((__half*)h0l)[tid] = __float2half_rn(hn);
    }
    __syncthreads();
    // ---- phase B: gi1 = wih1 * h0(t)
    float gi1 = bi1v;
    #pragma unroll
    for (int g = 0; g < 2; g++){
      uint4 hv[4];
      #pragma unroll
      for (int j = 0; j < 4; j++) hv[j] = h04[kh*8 + g*4 + j];
      #pragma unroll
      for (int j = 0; j < 4; j++){
        gi1 = dot2f(gi1, wi1[g*16 + j*4 + 0], hv[j].x);
        gi1 = dot2f(gi1, wi1[g*16 + j*4 + 1], hv[j].y);
        gi1 = dot2f(gi1, wi1[g*16 + j*4 + 2], hv[j].z);
        gi1 = dot2f(gi1, wi1[g*16 + j*4 + 3], hv[j].w);
      }
    }
    gi1 += __shfl_xor(gi1, 1);
    if (kh == 0) B0[r] = gi1;   // reuse (gates0 done)
    __syncthreads();
    // ---- gates layer 1 + h1 frag emission
    if (tid < HID){
      float rg = sigmoidf_(B0[tid]       + C1[tid]);
      float z  = sigmoidf_(B0[tid+HID]   + C1[tid+HID]);
      float nn = tanhf_   (B0[tid+2*HID] + rg*C1[tid+2*HID]);
      float hn = (1.0f - z)*nn + z*h1prev;
      h1prev = hn;
      ((__half*)h1l)[tid] = __float2half_rn(hn);
      h1af[t*10240 + (n>>4)*2560 + (tid>>3)*128 + (n&15)*8 + (tid&7)] = f2bf(hn);
    }
    __syncthreads();
  }
}

// ---------------- fc1: t-parallel MFMA, A = [h1;a] frags, B = w1 frags ----------------
__global__ __launch_bounds__(256) void k_fc1(const unsigned short* __restrict__ h1af,
                                             const unsigned short* __restrict__ w1f,
                                             const float* __restrict__ b1,
                                             unsigned short* __restrict__ fc1h){
  __shared__ float b1s[128];
  int t = blockIdx.x, tid = threadIdx.x;
  int wave = tid >> 6, lane = tid & 63, m = lane & 15, quad = lane >> 4;
  if (tid < 128) b1s[tid] = b1[tid];
  const uint4* A4 = (const uint4*)(h1af + t*10240);
  const uint4* B4 = (const uint4*)w1f;
  f32x4 acc[8];
  #pragma unroll
  for (int i = 0; i < 8; i++) acc[i] = (f32x4)(0.0f);
  #pragma unroll
  for (int ks = 0; ks < 5; ks++){
    uint4 av = A4[wave*320 + (ks*4 + quad)*16 + m];
    short8 avs = __builtin_bit_cast(short8, av);
    #pragma unroll
    for (int nt = 0; nt < 8; nt++){
      uint4 bv = B4[(ks*4 + quad)*128 + nt*16 + m];
      acc[nt] = __builtin_amdgcn_mfma_f32_16x16x32_bf16(avs, __builtin_bit_cast(short8, bv), acc[nt], 0, 0, 0);
    }
  }
  __syncthreads();
  #pragma unroll
  for (int nt = 0; nt < 8; nt++){
    float bj = b1s[nt*16 + m];
    #pragma unroll
    for (int rr = 0; rr < 4; rr++){
      float v = fmaxf(acc[nt][rr] + bj, 0.0f);
      fc1h[t*8192 + wave*2048 + (nt*2 + (m>>3))*128 + (quad*4 + rr)*8 + (m&7)] = f2bf(v);
    }
  }
}

// ---------------- minibatch discrimination: one block per (b, 4 t's) ----------------
__global__ __launch_bounds__(256) void k_disc(const unsigned short* __restrict__ fc1h,
                                              const unsigned short* __restrict__ tmh,
                                              float* __restrict__ O){
  __shared__ __align__(16) __half Mh[64*104];
  __shared__ float ps[64*18];
  int b = blockIdx.x;
  int tid = threadIdx.x;
  int wave = tid >> 6, lane = tid & 63, m = lane & 15, quad = lane >> 4;
  const uint4* Bg = (const uint4*)(tmh + b*(CDIM*HID));
  #pragma unroll 1
  for (int tt = 0; tt < 4; tt++){
    int t = blockIdx.y*4 + tt;
    const uint4* Ag = (const uint4*)(fc1h + t*8192);
    uint4 a4[4];
    #pragma unroll
    for (int kk = 0; kk < 4; kk++) a4[kk] = Ag[wave*256 + (kk*4 + quad)*16 + m];
    f32x4 acc[6];
    #pragma unroll
    for (int i = 0; i < 6; i++) acc[i] = (f32x4)(0.0f);
    #pragma unroll
    for (int kk = 0; kk < 4; kk++){
      short8 av = __builtin_bit_cast(short8, a4[kk]);
      #pragma unroll
      for (int nt = 0; nt < 6; nt++){
        uint4 b4 = Bg[(kk*4 + quad)*96 + nt*16 + m];
        acc[nt] = __builtin_amdgcn_mfma_f32_16x16x32_bf16(av, __builtin_bit_cast(short8, b4), acc[nt], 0, 0, 0);
      }
    }
    __syncthreads();   // prev-iteration readers done before Mh overwrite
    #pragma unroll
    for (int nt = 0; nt < 6; nt++){
      #pragma unroll
      for (int rr = 0; rr < 4; rr++){
        Mh[(rr*16 + wave*4 + quad)*104 + nt*16 + m] = __float2half(acc[nt][rr]);
      }
    }
    __syncthreads();
    const uint4* M4 = (const uint4*)Mh;
    if (tid < 240){
      int chalf = tid & 1, tp = tid >> 1;
      int rnd = tp >> 3, slot = tp & 7;
      int ta, tb;
      if (slot == 0){ ta = 15; tb = rnd; }
      else {
        ta = rnd + slot;      if (ta >= 15) ta -= 15;
        tb = rnd + 15 - slot; if (tb >= 15) tb -= 15;
      }
      float facc[16];
      #pragma unroll
      for (int p = 0; p < 16; p++) facc[p] = 0.0f;
      auto doChunk = [&](int c){
        int ch = chalf*6 + c;
        uint4 av[4], bv[4];
        #pragma unroll
        for (int s = 0; s < 4; s++){
          av[s] = M4[(s*16 + ta)*13 + ch];
          bv[s] = M4[(s*16 + tb)*13 + ch];
        }
        #pragma unroll
        for (int i = 0; i < 4; i++)
          #pragma unroll
          for (int j = 0; j < 4; j++)
            facc[i*4+j] = l1d4(facc[i*4+j], av[i], bv[j]);
      };
      doChunk(0); doChunk(1);
      bool big1 = true;
      #pragma unroll
      for (int p = 0; p < 16; p++) big1 = big1 && (facc[p] > 14.0f);
      if (!big1){
        doChunk(2); doChunk(3);
        bool big2 = true;
        #pragma unroll
        for (int p = 0; p < 16; p++) big2 = big2 && (facc[p] > 14.0f);
        if (!big2){ doChunk(4); doChunk(5); }
      }
      float tot[16];
      #pragma unroll
      for (int p = 0; p < 16; p++) tot[p] = facc[p] + __shfl_xor(facc[p], 1);
      if (chalf == 0){
        #pragma unroll
        for (int i = 0; i < 4; i++){
          float s = 0.0f;
          #pragma unroll
          for (int j = 0; j < 4; j++) s += __expf(-tot[i*4+j]);
          ps[(ta*4 + i)*18 + tb] = s;
        }
      } else {
        #pragma unroll
        for (int j = 0; j < 4; j++){
          float s = 0.0f;
          #pragma unroll
          for (int i = 0; i < 4; i++) s += __expf(-tot[i*4+j]);
          ps[(tb*4 + j)*18 + ta] = s;
        }
      }
    } else {
      int ta = tid - 240;
      float f6[6];
      #pragma unroll
      for (int p = 0; p < 6; p++) f6[p] = 0.0f;
      auto doChunkS = [&](int ch){
        uint4 rv[4];
        #pragma unroll
        for (int s = 0; s < 4; s++) rv[s] = M4[(s*16 + ta)*13 + ch];
        f6[0] = l1d4(f6[0], rv[0], rv[1]);
        f6[1] = l1d4(f6[1], rv[0], rv[2]);
        f6[2] = l1d4(f6[2], rv[0], rv[3]);
        f6[3] = l1d4(f6[3], rv[1], rv[2]);
        f6[4] = l1d4(f6[4], rv[1], rv[3]);
        f6[5] = l1d4(f6[5], rv[2], rv[3]);
      };
      doChunkS(0); doChunkS(1); doChunkS(2);
      bool big1 = true;
      #pragma unroll
      for (int p = 0; p < 6; p++) big1 = big1 && (f6[p] > 14.0f);
      if (!big1){
        doChunkS(3); doChunkS(4); doChunkS(5);
        bool big2 = true;
        #pragma unroll
        for (int p = 0; p < 6; p++) big2 = big2 && (f6[p] > 14.0f);
        if (!big2){
          doChunkS(6); doChunkS(7); doChunkS(8);
          doChunkS(9); doChunkS(10); doChunkS(11);
        }
      }
      float e01 = __expf(-f6[0]), e02 = __expf(-f6[1]), e03 = __expf(-f6[2]);
      float e12 = __expf(-f6[3]), e13 = __expf(-f6[4]), e23 = __expf(-f6[5]);
      ps[(ta*4 + 0)*18 + ta] = e01 + e02 + e03;
      ps[(ta*4 + 1)*18 + ta] = e01 + e12 + e13;
      ps[(ta*4 + 2)*18 + ta] = e02 + e12 + e23;
      ps[(ta*4 + 3)*18 + ta] = e03 + e13 + e23;
    }
    __syncthreads();
    if (tid < NB){
      float s = 0.0f;
      #pragma unroll
      for (int k = 0; k < 16; k++) s += ps[tid*18 + k];
      O[(t*HID + b)*NB + tid] = s*(1.0f/63.0f);
    }
  }
}

// ---------------- final: reads fc1 bf16 frags + O ----------------
__global__ __launch_bounds__(256) void k_final(const unsigned short* __restrict__ fc1h,
                                               const float* __restrict__ O,
                                               const float* __restrict__ w2, const float* __restrict__ b2,
                                               float* __restrict__ out){
  __shared__ float ol[NB*HID];            // [b][n]
  __shared__ unsigned short fr[8192];     // fc1 frags for this t
  __shared__ float wl[2*HID + 2];
  int t = blockIdx.x, tid = threadIdx.x;
  for (int i = tid; i < NB*HID; i += 256) ol[i] = O[t*NB*HID + i];
  const uint4* Fg = (const uint4*)(fc1h + t*8192);
  for (int i = tid; i < 1024; i += 256) ((uint4*)fr)[i] = Fg[i];
  if (tid < 2*HID) wl[tid] = w2[tid];
  if (tid == 0) wl[2*HID] = b2[0];
  __syncthreads();
  if (tid < NB){
    float acc = wl[2*HID];
    int base = (tid>>4)*2048 + (tid&15)*8;
    #pragma unroll 8
    for (int j = 0; j < HID; j++) acc += bf2f(fr[base + (j>>3)*128 + (j&7)])*wl[j];
    #pragma unroll 8
    for (int b = 0; b < HID; b++) acc += ol[b*NB + tid]*wl[HID + b];
    out[t*NB + tid] = sigmoidf_(acc);
  }
}

extern "C" void kernel_launch(void* const* d_in, const int* in_sizes, int n_in,
                              void* d_out, int out_size, void* d_ws, size_t ws_size,
                              hipStream_t stream){
  const float* x    = (const float*)d_in[0];
  const float* a    = (const float*)d_in[1];
  const float* wih0 = (const float*)d_in[2];
  const float* whh0 = (const float*)d_in[3];
  const float* bih0 = (const float*)d_in[4];
  const float* bhh0 = (const float*)d_in[5];
  const float* wih1 = (const float*)d_in[6];
  const float* whh1 = (const float*)d_in[7];
  const float* bih1 = (const float*)d_in[8];
  const float* bhh1 = (const float*)d_in[9];
  const float* w1   = (const float*)d_in[10];
  const float* b1   = (const float*)d_in[11];
  const float* w2   = (const float*)d_in[12];
  const float* b2   = (const float*)d_in[13];
  const float* Tm   = (const float*)d_in[14];
  float* ws = (float*)d_ws;
  float* Ows = ws;                                           // 262144 floats
  unsigned int* wih0p = (unsigned int*)(ws + 262144);        // 12288
  unsigned int* whh0p = (unsigned int*)(ws + 274432);        // 24576
  unsigned int* wih1p = (unsigned int*)(ws + 299008);        // 24576
  unsigned int* whh1p = (unsigned int*)(ws + 323584);        // 24576
  unsigned short* tmh  = (unsigned short*)(ws + 348160);     // 1572864 ushorts
  unsigned short* fc1h = (unsigned short*)(ws + 1134592);    // 262144 ushorts
  unsigned short* h1af = (unsigned short*)(ws + 1265664);    // 327680 ushorts
  unsigned short* w1f  = (unsigned short*)(ws + 1429504);    // 20480 ushorts
  float* out = (float*)d_out;

  k_prep<<<dim3(152), dim3(256), 0, stream>>>(Tm, tmh, wih0, whh0, wih1, whh1, w1, a,
                                              wih0p, whh0p, wih1p, whh1p, w1f, h1af);
  k_gruF<<<dim3(NB), dim3(768), 0, stream>>>(x, wih0p, whh0p, wih1p, whh1p,
                                             bih0, bhh0, bih1, bhh1, h1af);
  k_fc1<<<dim3(T_STEPS), dim3(256), 0, stream>>>(h1af, w1f, b1, fc1h);
  k_disc<<<dim3(HID, T_STEPS/4), dim3(256), 0, stream>>>(fc1h, tmh, Ows);
  k_final<<<dim3(T_STEPS), dim3(256), 0, stream>>>(fc1h, Ows, w2, b2, out);
}

// Round 6
// 210.186 us; speedup vs baseline: 1.1655x; 1.1655x over previous
//
#include <hip/hip_runtime.h>
#include <hip/hip_fp16.h>
#include <cstdint>

#define T_STEPS 32
#define NB 64
#define STATE 64
#define HID 128
#define ACT 32
#define CDIM 96
#define G3 (3*HID)   // 384

typedef __attribute__((ext_vector_type(8))) short short8;
typedef __attribute__((ext_vector_type(4))) float f32x4;
typedef _Float16 h2v __attribute__((ext_vector_type(2)));

__device__ __forceinline__ unsigned short f2bf(float f){
  unsigned int u = __builtin_bit_cast(unsigned int, f);
  u = u + 0x7FFFu + ((u >> 16) & 1u);
  return (unsigned short)(u >> 16);
}
__device__ __forceinline__ float bf2f(unsigned short u){
  unsigned int v = ((unsigned int)u) << 16; return __builtin_bit_cast(float, v);
}
__device__ __forceinline__ unsigned int packh2(float f0, float f1){
  return (unsigned int)__half_as_ushort(__float2half_rn(f0)) |
         ((unsigned int)__half_as_ushort(__float2half_rn(f1)) << 16);
}
__device__ __forceinline__ float sigmoidf_(float x){ return 1.0f/(1.0f + __expf(-x)); }
__device__ __forceinline__ float tanhf_(float x){ float e = __expf(2.0f*x); return (e-1.0f)/(e+1.0f); }

__device__ __forceinline__ float dot2f(float acc, unsigned int a, unsigned int b){
  h2v av = __builtin_bit_cast(h2v, a);
  h2v bv = __builtin_bit_cast(h2v, b);
  return __builtin_amdgcn_fdot2(av, bv, acc, false);
}
__device__ __forceinline__ float l1d(float acc, unsigned int ua, unsigned int ub){
  __half2 a = __builtin_bit_cast(__half2, ua);
  __half2 b = __builtin_bit_cast(__half2, ub);
  __half2 d = __habs2(__hsub2(a, b));
  h2v dv = __builtin_bit_cast(h2v, d);
  h2v ones; ones[0] = (_Float16)1.0f; ones[1] = (_Float16)1.0f;
  return __builtin_amdgcn_fdot2(dv, ones, acc, false);
}
__device__ __forceinline__ float l1d4(float acc, uint4 a, uint4 b){
  acc = l1d(acc, a.x, b.x); acc = l1d(acc, a.y, b.y);
  acc = l1d(acc, a.z, b.z); acc = l1d(acc, a.w, b.w);
  return acc;
}

// ---------------- prep ----------------
// 0..127   : tmh (Tm -> bf16 B-frag order per b)
// 128..131 : whh0p, whh1p fp16-packed [k2][r]
// 132..135 : w1f  (w1 -> bf16 B-frag, 20480)
// 136..139 : wi0f (wih0 -> bf16 B-frag, K=64, 24576)
// 140..143 : wi1f (wih1 -> bf16 B-frag, K=128, 49152)
// 144..155 : xaf  (x -> bf16 A-frag, 131072)
// 156..167 : a -> bf16 A-frag chunks 16..19 of h1af (65536)
__global__ void k_prep(const float* __restrict__ Tm, unsigned short* __restrict__ tmh,
                       const float* __restrict__ whh0, const float* __restrict__ whh1,
                       const float* __restrict__ w1, const float* __restrict__ wih0,
                       const float* __restrict__ wih1, const float* __restrict__ x,
                       const float* __restrict__ a,
                       unsigned int* __restrict__ whh0p, unsigned int* __restrict__ whh1p,
                       unsigned short* __restrict__ w1f, unsigned short* __restrict__ wi0f,
                       unsigned short* __restrict__ wi1f, unsigned short* __restrict__ xaf,
                       unsigned short* __restrict__ h1af){
  int tid = threadIdx.x;
  int bx = blockIdx.x;
  if (bx < 128){
    int b = bx;
    for (int e = tid; e < HID*CDIM; e += 256){
      int chunk = e / 768;
      int r1 = e - chunk*768;
      int c = r1 >> 3, h = r1 & 7;
      int k = chunk*8 + h;
      tmh[b*(HID*CDIM) + e] = f2bf(Tm[k*(HID*CDIM) + b*CDIM + c]);
    }
  } else if (bx < 132){
    for (int e = (bx-128)*256 + tid; e < 24576; e += 1024){
      int k2 = e / 384, r = e - k2*384;
      whh0p[e] = packh2(whh0[r*128 + 2*k2], whh0[r*128 + 2*k2 + 1]);
      whh1p[e] = packh2(whh1[r*128 + 2*k2], whh1[r*128 + 2*k2 + 1]);
    }
  } else if (bx < 136){
    for (int e = (bx-132)*256 + tid; e < 20480; e += 1024){
      int kc = e >> 10, rem = e & 1023;
      int col = rem >> 3, j = rem & 7;
      w1f[e] = f2bf(w1[col*160 + kc*8 + j]);
    }
  } else if (bx < 140){
    for (int e = (bx-136)*256 + tid; e < 24576; e += 1024){
      int kc = e / 3072, rem = e - kc*3072;
      int col = rem >> 3, kl = rem & 7;
      wi0f[e] = f2bf(wih0[col*64 + kc*8 + kl]);
    }
  } else if (bx < 144){
    for (int e = (bx-140)*256 + tid; e < 49152; e += 1024){
      int kc = e / 3072, rem = e - kc*3072;
      int col = rem >> 3, kl = rem & 7;
      wi1f[e] = f2bf(wih1[col*128 + kc*8 + kl]);
    }
  } else if (bx < 156){
    for (int e = (bx-144)*256 + tid; e < 131072; e += 3072){
      int t = e >> 12, rem = e & 4095;
      int ntile = rem >> 10, rem2 = rem & 1023;
      int kc = rem2 >> 7, nl = (rem2 >> 3) & 15, kl = rem2 & 7;
      int n = ntile*16 + nl, k = kc*8 + kl;
      xaf[e] = f2bf(x[t*4096 + n*64 + k]);
    }
  } else {
    for (int e = (bx-156)*256 + tid; e < 65536; e += 3072){
      int t = e >> 11, rem = e & 2047;
      int n = rem >> 5, c = rem & 31;
      int pos = t*10240 + (n>>4)*2560 + (16 + (c>>3))*128 + (n&15)*8 + (c&7);
      h1af[pos] = f2bf(a[t*(NB*ACT) + n*ACT + c]);
    }
  }
}

// ---------------- gi GEMM (t-parallel MFMA): gig[t][n][col] = afrag@wfrag + bias ----------------
// KK = number of K32 chunks (2 for K=64, 4 for K=128); TSU = A uint4 stride per t.
template<int KK, int TSU>
__global__ __launch_bounds__(256) void k_gi(const unsigned short* __restrict__ af,
                                            const unsigned short* __restrict__ wf,
                                            const float* __restrict__ bias,
                                            float* __restrict__ gig){
  int t = blockIdx.x, by = blockIdx.y, tid = threadIdx.x;
  int wave = tid >> 6, lane = tid & 63, m = lane & 15, quad = lane >> 4;
  const uint4* A4 = (const uint4*)af;
  const uint4* B4 = (const uint4*)wf;
  uint4 av[KK];
  #pragma unroll
  for (int kk = 0; kk < KK; kk++) av[kk] = A4[t*TSU + wave*(TSU/4) + (kk*4+quad)*16 + m];
  f32x4 acc[6];
  #pragma unroll
  for (int i = 0; i < 6; i++) acc[i] = (f32x4)(0.0f);
  #pragma unroll
  for (int kk = 0; kk < KK; kk++){
    short8 a = __builtin_bit_cast(short8, av[kk]);
    #pragma unroll
    for (int ntl = 0; ntl < 6; ntl++){
      int nt = by*6 + ntl;
      uint4 bv = B4[(kk*4+quad)*384 + nt*16 + m];
      acc[ntl] = __builtin_amdgcn_mfma_f32_16x16x32_bf16(a, __builtin_bit_cast(short8, bv), acc[ntl], 0, 0, 0);
    }
  }
  #pragma unroll
  for (int ntl = 0; ntl < 6; ntl++){
    int col = (by*6+ntl)*16 + m;
    float bv = bias[col];
    #pragma unroll
    for (int rr = 0; rr < 4; rr++){
      int n = wave*16 + quad*4 + rr;
      gig[(t*NB + n)*G3 + col] = acc[ntl][rr] + bv;
    }
  }
}

// ---------------- GRU recurrence (one layer): one block per sample, whh in 32 VGPRs ----------------
// TS/NS: output bf16 A-frag strides (layer0: 8192/2048 for k_gi1; layer1: 10240/2560 for k_fc1).
template<int TS, int NS>
__global__ __launch_bounds__(768, 3) void k_rec(const unsigned int* __restrict__ whhp,
                                                const float* __restrict__ bhh,
                                                const float* __restrict__ gig,
                                                unsigned short* __restrict__ haf){
  __shared__ __align__(16) unsigned int hl[64];   // h fp16-packed
  __shared__ float A0[G3];
  int n = blockIdx.x, tid = threadIdx.x;
  int r = tid >> 1, kh = tid & 1;
  unsigned int wh[32];
  #pragma unroll
  for (int i = 0; i < 32; i++) wh[i] = whhp[(kh*32 + i)*384 + r];
  float bh = (kh == 0) ? bhh[r] : 0.0f;
  if (tid < 64) hl[tid] = 0u;
  float g_r = 0.0f, g_z = 0.0f, g_n = 0.0f, hprev = 0.0f;
  if (tid < HID){
    const float* gp = gig + n*G3 + tid;
    g_r = gp[0]; g_z = gp[HID]; g_n = gp[2*HID];
  }
  __syncthreads();
  const uint4* h4 = (const uint4*)hl;
  for (int t = 0; t < T_STEPS; t++){
    float gh = bh;
    #pragma unroll
    for (int g = 0; g < 2; g++){
      uint4 hv[4];
      #pragma unroll
      for (int j = 0; j < 4; j++) hv[j] = h4[kh*8 + g*4 + j];
      #pragma unroll
      for (int j = 0; j < 4; j++){
        gh = dot2f(gh, wh[g*16 + j*4 + 0], hv[j].x);
        gh = dot2f(gh, wh[g*16 + j*4 + 1], hv[j].y);
        gh = dot2f(gh, wh[g*16 + j*4 + 2], hv[j].z);
        gh = dot2f(gh, wh[g*16 + j*4 + 3], hv[j].w);
      }
    }
    gh += __shfl_xor(gh, 1);
    if (kh == 0) A0[r] = gh;
    __syncthreads();
    if (tid < HID){
      float cr = g_r, cz = g_z, cn = g_n;
      int tn2 = (t+1 < T_STEPS) ? t+1 : t;     // prefetch next step's gi
      const float* gp = gig + (tn2*NB + n)*G3 + tid;
      g_r = gp[0]; g_z = gp[HID]; g_n = gp[2*HID];
      float rg = sigmoidf_(cr + A0[tid]);
      float z  = sigmoidf_(cz + A0[tid+HID]);
      float nn = tanhf_   (cn + rg*A0[tid+2*HID]);
      float hn = (1.0f - z)*nn + z*hprev;
      hprev = hn;
      ((__half*)hl)[tid] = __float2half_rn(hn);
      haf[t*TS + (n>>4)*NS + (tid>>3)*128 + (n&15)*8 + (tid&7)] = f2bf(hn);
    }
    __syncthreads();
  }
}

// ---------------- fc1: t-parallel MFMA, A = [h1;a] frags, B = w1 frags ----------------
__global__ __launch_bounds__(256) void k_fc1(const unsigned short* __restrict__ h1af,
                                             const unsigned short* __restrict__ w1f,
                                             const float* __restrict__ b1,
                                             unsigned short* __restrict__ fc1h){
  __shared__ float b1s[128];
  int t = blockIdx.x, tid = threadIdx.x;
  int wave = tid >> 6, lane = tid & 63, m = lane & 15, quad = lane >> 4;
  if (tid < 128) b1s[tid] = b1[tid];
  const uint4* A4 = (const uint4*)(h1af + t*10240);
  const uint4* B4 = (const uint4*)w1f;
  f32x4 acc[8];
  #pragma unroll
  for (int i = 0; i < 8; i++) acc[i] = (f32x4)(0.0f);
  #pragma unroll
  for (int ks = 0; ks < 5; ks++){
    uint4 av = A4[wave*320 + (ks*4 + quad)*16 + m];
    short8 avs = __builtin_bit_cast(short8, av);
    #pragma unroll
    for (int nt = 0; nt < 8; nt++){
      uint4 bv = B4[(ks*4 + quad)*128 + nt*16 + m];
      acc[nt] = __builtin_amdgcn_mfma_f32_16x16x32_bf16(avs, __builtin_bit_cast(short8, bv), acc[nt], 0, 0, 0);
    }
  }
  __syncthreads();
  #pragma unroll
  for (int nt = 0; nt < 8; nt++){
    float bj = b1s[nt*16 + m];
    #pragma unroll
    for (int rr = 0; rr < 4; rr++){
      float v = fmaxf(acc[nt][rr] + bj, 0.0f);
      fc1h[t*8192 + wave*2048 + (nt*2 + (m>>3))*128 + (quad*4 + rr)*8 + (m&7)] = f2bf(v);
    }
  }
}

// ---------------- minibatch discrimination: one block per (b, 4 t's) ----------------
__global__ __launch_bounds__(256) void k_disc(const unsigned short* __restrict__ fc1h,
                                              const unsigned short* __restrict__ tmh,
                                              float* __restrict__ O){
  __shared__ __align__(16) __half Mh[64*104];
  __shared__ float ps[64*18];
  int b = blockIdx.x;
  int tid = threadIdx.x;
  int wave = tid >> 6, lane = tid & 63, m = lane & 15, quad = lane >> 4;
  const uint4* Bg = (const uint4*)(tmh + b*(CDIM*HID));
  #pragma unroll 1
  for (int tt = 0; tt < 4; tt++){
    int t = blockIdx.y*4 + tt;
    const uint4* Ag = (const uint4*)(fc1h + t*8192);
    uint4 a4[4];
    #pragma unroll
    for (int kk = 0; kk < 4; kk++) a4[kk] = Ag[wave*256 + (kk*4 + quad)*16 + m];
    f32x4 acc[6];
    #pragma unroll
    for (int i = 0; i < 6; i++) acc[i] = (f32x4)(0.0f);
    #pragma unroll
    for (int kk = 0; kk < 4; kk++){
      short8 av = __builtin_bit_cast(short8, a4[kk]);
      #pragma unroll
      for (int nt = 0; nt < 6; nt++){
        uint4 b4 = Bg[(kk*4 + quad)*96 + nt*16 + m];
        acc[nt] = __builtin_amdgcn_mfma_f32_16x16x32_bf16(av, __builtin_bit_cast(short8, b4), acc[nt], 0, 0, 0);
      }
    }
    __syncthreads();   // prev-iteration readers done before Mh overwrite
    #pragma unroll
    for (int nt = 0; nt < 6; nt++){
      #pragma unroll
      for (int rr = 0; rr < 4; rr++){
        Mh[(rr*16 + wave*4 + quad)*104 + nt*16 + m] = __float2half(acc[nt][rr]);
      }
    }
    __syncthreads();
    const uint4* M4 = (const uint4*)Mh;
    if (tid < 240){
      int chalf = tid & 1, tp = tid >> 1;
      int rnd = tp >> 3, slot = tp & 7;
      int ta, tb;
      if (slot == 0){ ta = 15; tb = rnd; }
      else {
        ta = rnd + slot;      if (ta >= 15) ta -= 15;
        tb = rnd + 15 - slot; if (tb >= 15) tb -= 15;
      }
      float facc[16];
      #pragma unroll
      for (int p = 0; p < 16; p++) facc[p] = 0.0f;
      auto doChunk = [&](int c){
        int ch = chalf*6 + c;
        uint4 av[4], bv[4];
        #pragma unroll
        for (int s = 0; s < 4; s++){
          av[s] = M4[(s*16 + ta)*13 + ch];
          bv[s] = M4[(s*16 + tb)*13 + ch];
        }
        #pragma unroll
        for (int i = 0; i < 4; i++)
          #pragma unroll
          for (int j = 0; j < 4; j++)
            facc[i*4+j] = l1d4(facc[i*4+j], av[i], bv[j]);
      };
      doChunk(0); doChunk(1);
      bool big1 = true;
      #pragma unroll
      for (int p = 0; p < 16; p++) big1 = big1 && (facc[p] > 14.0f);
      if (!big1){
        doChunk(2); doChunk(3);
        bool big2 = true;
        #pragma unroll
        for (int p = 0; p < 16; p++) big2 = big2 && (facc[p] > 14.0f);
        if (!big2){ doChunk(4); doChunk(5); }
      }
      float tot[16];
      #pragma unroll
      for (int p = 0; p < 16; p++) tot[p] = facc[p] + __shfl_xor(facc[p], 1);
      if (chalf == 0){
        #pragma unroll
        for (int i = 0; i < 4; i++){
          float s = 0.0f;
          #pragma unroll
          for (int j = 0; j < 4; j++) s += __expf(-tot[i*4+j]);
          ps[(ta*4 + i)*18 + tb] = s;
        }
      } else {
        #pragma unroll
        for (int j = 0; j < 4; j++){
          float s = 0.0f;
          #pragma unroll
          for (int i = 0; i < 4; i++) s += __expf(-tot[i*4+j]);
          ps[(tb*4 + j)*18 + ta] = s;
        }
      }
    } else {
      int ta = tid - 240;
      float f6[6];
      #pragma unroll
      for (int p = 0; p < 6; p++) f6[p] = 0.0f;
      auto doChunkS = [&](int ch){
        uint4 rv[4];
        #pragma unroll
        for (int s = 0; s < 4; s++) rv[s] = M4[(s*16 + ta)*13 + ch];
        f6[0] = l1d4(f6[0], rv[0], rv[1]);
        f6[1] = l1d4(f6[1], rv[0], rv[2]);
        f6[2] = l1d4(f6[2], rv[0], rv[3]);
        f6[3] = l1d4(f6[3], rv[1], rv[2]);
        f6[4] = l1d4(f6[4], rv[1], rv[3]);
        f6[5] = l1d4(f6[5], rv[2], rv[3]);
      };
      doChunkS(0); doChunkS(1); doChunkS(2);
      bool big1 = true;
      #pragma unroll
      for (int p = 0; p < 6; p++) big1 = big1 && (f6[p] > 14.0f);
      if (!big1){
        doChunkS(3); doChunkS(4); doChunkS(5);
        bool big2 = true;
        #pragma unroll
        for (int p = 0; p < 6; p++) big2 = big2 && (f6[p] > 14.0f);
        if (!big2){
          doChunkS(6); doChunkS(7); doChunkS(8);
          doChunkS(9); doChunkS(10); doChunkS(11);
        }
      }
      float e01 = __expf(-f6[0]), e02 = __expf(-f6[1]), e03 = __expf(-f6[2]);
      float e12 = __expf(-f6[3]), e13 = __expf(-f6[4]), e23 = __expf(-f6[5]);
      ps[(ta*4 + 0)*18 + ta] = e01 + e02 + e03;
      ps[(ta*4 + 1)*18 + ta] = e01 + e12 + e13;
      ps[(ta*4 + 2)*18 + ta] = e02 + e12 + e23;
      ps[(ta*4 + 3)*18 + ta] = e03 + e13 + e23;
    }
    __syncthreads();
    if (tid < NB){
      float s = 0.0f;
      #pragma unroll
      for (int k = 0; k < 16; k++) s += ps[tid*18 + k];
      O[(t*HID + b)*NB + tid] = s*(1.0f/63.0f);
    }
  }
}

// ---------------- final: reads fc1 bf16 frags + O ----------------
__global__ __launch_bounds__(256) void k_final(const unsigned short* __restrict__ fc1h,
                                               const float* __restrict__ O,
                                               const float* __restrict__ w2, const float* __restrict__ b2,
                                               float* __restrict__ out){
  __shared__ float ol[NB*HID];            // [b][n]
  __shared__ unsigned short fr[8192];     // fc1 frags for this t
  __shared__ float wl[2*HID + 2];
  int t = blockIdx.x, tid = threadIdx.x;
  for (int i = tid; i < NB*HID; i += 256) ol[i] = O[t*NB*HID + i];
  const uint4* Fg = (const uint4*)(fc1h + t*8192);
  for (int i = tid; i < 1024; i += 256) ((uint4*)fr)[i] = Fg[i];
  if (tid < 2*HID) wl[tid] = w2[tid];
  if (tid == 0) wl[2*HID] = b2[0];
  __syncthreads();
  if (tid < NB){
    float acc = wl[2*HID];
    int base = (tid>>4)*2048 + (tid&15)*8;
    #pragma unroll 8
    for (int j = 0; j < HID; j++) acc += bf2f(fr[base + (j>>3)*128 + (j&7)])*wl[j];
    #pragma unroll 8
    for (int b = 0; b < HID; b++) acc += ol[b*NB + tid]*wl[HID + b];
    out[t*NB + tid] = sigmoidf_(acc);
  }
}

extern "C" void kernel_launch(void* const* d_in, const int* in_sizes, int n_in,
                              void* d_out, int out_size, void* d_ws, size_t ws_size,
                              hipStream_t stream){
  const float* x    = (const float*)d_in[0];
  const float* a    = (const float*)d_in[1];
  const float* wih0 = (const float*)d_in[2];
  const float* whh0 = (const float*)d_in[3];
  const float* bih0 = (const float*)d_in[4];
  const float* bhh0 = (const float*)d_in[5];
  const float* wih1 = (const float*)d_in[6];
  const float* whh1 = (const float*)d_in[7];
  const float* bih1 = (const float*)d_in[8];
  const float* bhh1 = (const float*)d_in[9];
  const float* w1   = (const float*)d_in[10];
  const float* b1   = (const float*)d_in[11];
  const float* w2   = (const float*)d_in[12];
  const float* b2   = (const float*)d_in[13];
  const float* Tm   = (const float*)d_in[14];
  float* ws = (float*)d_ws;
  float* Ows = ws;                                          // 262144 floats
  unsigned int* whh0p = (unsigned int*)(ws + 262144);       // 24576 dwords
  unsigned int* whh1p = (unsigned int*)(ws + 286720);       // 24576
  unsigned short* tmh  = (unsigned short*)(ws + 311296);    // 1572864 ushorts
  unsigned short* fc1h = (unsigned short*)(ws + 1097728);   // 262144 ushorts
  unsigned short* h1af = (unsigned short*)(ws + 1228800);   // 327680 ushorts
  unsigned short* w1f  = (unsigned short*)(ws + 1392640);   // 20480 ushorts
  unsigned short* xaf  = (unsigned short*)(ws + 1402880);   // 131072 ushorts
  unsigned short* wi0f = (unsigned short*)(ws + 1468416);   // 24576 ushorts
  unsigned short* wi1f = (unsigned short*)(ws + 1480704);   // 49152 ushorts
  unsigned short* h0af = (unsigned short*)(ws + 1505280);   // 262144 ushorts
  float* gig = ws + 1636352;                                // 786432 floats (gi0, then reused as gi1)
  float* out = (float*)d_out;

  k_prep<<<dim3(168), dim3(256), 0, stream>>>(Tm, tmh, whh0, whh1, w1, wih0, wih1, x, a,
                                              whh0p, whh1p, w1f, wi0f, wi1f, xaf, h1af);
  k_gi<2, 512><<<dim3(T_STEPS, 4), dim3(256), 0, stream>>>(xaf, wi0f, bih0, gig);
  k_rec<8192, 2048><<<dim3(NB), dim3(768), 0, stream>>>(whh0p, bhh0, gig, h0af);
  k_gi<4, 1024><<<dim3(T_STEPS, 4), dim3(256), 0, stream>>>(h0af, wi1f, bih1, gig);
  k_rec<10240, 2560><<<dim3(NB), dim3(768), 0, stream>>>(whh1p, bhh1, gig, h1af);
  k_fc1<<<dim3(T_STEPS), dim3(256), 0, stream>>>(h1af, w1f, b1, fc1h);
  k_disc<<<dim3(HID, T_STEPS/4), dim3(256), 0, stream>>>(fc1h, tmh, Ows);
  k_final<<<dim3(T_STEPS), dim3(256), 0, stream>>>(fc1h, Ows, w2, b2, out);
}